// Round 3
// baseline (774.579 us; speedup 1.0000x reference)
//
#include <hip/hip_runtime.h>

typedef unsigned short ushort_t;
typedef float f32x4 __attribute__((ext_vector_type(4)));
typedef short s16x8 __attribute__((ext_vector_type(8)));

#define BROWS 4096
#define DIMK  1024
#define RANKK 256
#define TROWS 16

#define DTF 0.01f
#define THETAF 1.35120719195965763f
#define C1F    0.675603595979828816f   // THETA/2
#define C2F   (-0.175603595979828816f) // (1-THETA)/2
#define D1F    1.35120719195965763f    // THETA
#define D2F   (-1.70241438391931526f)  // 1-2*THETA

__device__ __forceinline__ ushort_t f2bf(float f) {
    unsigned u = __builtin_bit_cast(unsigned, f);
    return (ushort_t)((u + 0x7FFFu + ((u >> 16) & 1u)) >> 16);
}

// ---------------------------------------------------------------------------
// Transpose + cast f32 -> bf16:  out[c][r] = bf16(in[r][c]),  in is [R][C].
// ---------------------------------------------------------------------------
__global__ void fr_transpose_cast(const float* __restrict__ in,
                                  ushort_t* __restrict__ out, int R, int C) {
    __shared__ float tile[32][33];
    int tiles_c = C >> 5;
    int tr = blockIdx.x / tiles_c;
    int tc = blockIdx.x % tiles_c;
    int tx = threadIdx.x & 31;
    int ty = threadIdx.x >> 5;
#pragma unroll
    for (int i = 0; i < 32; i += 8)
        tile[ty + i][tx] = in[(size_t)(tr * 32 + ty + i) * C + tc * 32 + tx];
    __syncthreads();
#pragma unroll
    for (int i = 0; i < 32; i += 8)
        out[(size_t)(tc * 32 + ty + i) * R + tr * 32 + tx] = f2bf(tile[tx][ty + i]);
}

// ---------------------------------------------------------------------------
// Fused Forest-Ruth integrator. Block = 16 rows, 512 threads (8 waves).
// Round-1 structure + explicit double-buffered register prefetch of the
// B-fragments (per-lane 16B loads, L2-resident) to build MLP. Cross-phase
// prefetch: next phase's first two load-slots are issued during the current
// phase's tail; __syncthreads' vmcnt(0) drain completes them.
// ---------------------------------------------------------------------------

// phase-1 group g covers kk = 2g, 2g+1; BUF = 4 x s16x8 (b0,b1 per kk)
#define P1L(g, BUF) do {                                                      \
    _Pragma("unroll")                                                         \
    for (int t = 0; t < 2; ++t) {                                             \
        const int kk_ = 2 * (g) + t;                                          \
        BUF[2 * t]     = b0p[kk_ * 4];                                        \
        BUF[2 * t + 1] = b1p[kk_ * 4];                                        \
    }                                                                         \
} while (0)

#define P1G(g, BUF) do {                                                      \
    _Pragma("unroll")                                                         \
    for (int t = 0; t < 2; ++t) {                                             \
        const int kk_ = 2 * (g) + t;                                          \
        const int kel_ = kk_ * 32 + g4 * 8;                                   \
        const s16x8 a_ = *(const s16x8*)&vb[m16 * DIMK + (kel_ ^ swz)];       \
        h0 = __builtin_amdgcn_mfma_f32_16x16x32_bf16(a_, BUF[2 * t], h0, 0, 0, 0);     \
        h1 = __builtin_amdgcn_mfma_f32_16x16x32_bf16(a_, BUF[2 * t + 1], h1, 0, 0, 0); \
    }                                                                         \
} while (0)

// phase-2 slot s = kk*2 + half; BUF = 4 x s16x8 (nt = half*4 + q)
#define P2L(s, BUF) do {                                                      \
    const int kk_ = (s) >> 1, hf_ = (s) & 1;                                  \
    _Pragma("unroll")                                                         \
    for (int q = 0; q < 4; ++q) BUF[q] = bwp[(hf_ * 4 + q) * 512 + kk_ * 4];  \
} while (0)

#define P2G(s, BUF) do {                                                      \
    const int kk_ = (s) >> 1, hf_ = (s) & 1;                                  \
    const int kel_ = kk_ * 32 + g4 * 8;                                       \
    const s16x8 a_ = *(const s16x8*)&gb[m16 * RANKK + (kel_ ^ swz)];          \
    _Pragma("unroll")                                                         \
    for (int q = 0; q < 4; ++q)                                               \
        acc[hf_ * 4 + q] = __builtin_amdgcn_mfma_f32_16x16x32_bf16(           \
            a_, BUF[q], acc[hf_ * 4 + q], 0, 0, 0);                           \
} while (0)

__global__ __launch_bounds__(512, 2) void fr_kernel(
    const float* __restrict__ x_in, const float* __restrict__ v_in,
    const float* __restrict__ f_in, const ushort_t* __restrict__ Ut,
    const ushort_t* __restrict__ Wt, const int* __restrict__ steps_p,
    float* __restrict__ out) {
    __shared__ ushort_t vb[TROWS * DIMK];    // 32 KB, XOR-swizzled rows
    __shared__ ushort_t gb[TROWS * RANKK];   // 8 KB, XOR-swizzled rows

    const int tid  = threadIdx.x;
    const int lane = tid & 63;
    const int wave = tid >> 6;          // 0..7
    const int m16  = lane & 15;
    const int g4   = lane >> 4;         // 0..3
    const int swz  = (m16 & 7) << 3;    // XOR swizzle (element index bits 3-5)
    const int row0 = blockIdx.x * TROWS;
    const int n_acc = 3 * steps_p[0];

    // fragment ownership: i = nt*4 + r;  m = g4*4 + r;  n = wave*128 + nt*16 + m16
    float vreg[32], xreg[32], freg[32];
#pragma unroll
    for (int nt = 0; nt < 8; ++nt) {
#pragma unroll
        for (int r = 0; r < 4; ++r) {
            const int m = g4 * 4 + r;
            const int n = wave * 128 + nt * 16 + m16;
            const size_t gi = (size_t)(row0 + m) * DIMK + n;
            const float v0 = v_in[gi];
            vreg[nt * 4 + r] = v0;
            xreg[nt * 4 + r] = x_in[gi] + (C1F * DTF) * v0;  // first x-substep folded
            freg[nt * 4 + r] = f_in[gi];
            vb[m * DIMK + (n ^ ((m & 7) << 3))] = f2bf(v0);
        }
    }

    // B-fragment pointers (16-byte per-lane loads)
    const s16x8* b0p = (const s16x8*)(Ut + (size_t)(wave * 32 + m16) * DIMK + g4 * 8);
    const s16x8* b1p = b0p + (16 * DIMK) / 8;
    const s16x8* bwp = (const s16x8*)(Wt + (size_t)(wave * 128 + m16) * RANKK + g4 * 8);
    const int n1a = wave * 32 + m16, n1b = n1a + 16;

    s16x8 pA[4], pB[4], q0[4], q1[4];
    P1L(0, pA);
    P1L(1, pB);
    __syncthreads();   // vb ready; pA/pB loads drained

    for (int j = 0; j < n_acc; ++j) {
        // ================= phase 1: h = v @ U ===============================
        f32x4 h0 = {0.f, 0.f, 0.f, 0.f}, h1 = {0.f, 0.f, 0.f, 0.f};
        f32x4 acc[8];
#pragma unroll
        for (int nt = 0; nt < 8; ++nt) acc[nt] = (f32x4){0.f, 0.f, 0.f, 0.f};

        P1G(0, pA);  P1L(2, pA);
        P1G(1, pB);  P1L(3, pB);
        P1G(2, pA);  P1L(4, pA);
        P1G(3, pB);  P1L(5, pB);
        P1G(4, pA);  P1L(6, pA);
        P1G(5, pB);  P1L(7, pB);
        P1G(6, pA);  P1L(8, pA);
        P1G(7, pB);  P1L(9, pB);
        P1G(8, pA);  P1L(10, pA);
        P1G(9, pB);  P1L(11, pB);
        P1G(10, pA); P1L(12, pA);
        P1G(11, pB); P1L(13, pB);
        P1G(12, pA); P1L(14, pA);
        P1G(13, pB); P1L(15, pB);
        P1G(14, pA); P2L(0, q0);   // prefetch phase-2 slots 0,1
        P1G(15, pB); P2L(1, q1);

        // g = h*h -> gb (XOR-swizzled like vb)
#pragma unroll
        for (int r = 0; r < 4; ++r) {
            const int m = g4 * 4 + r;
            gb[m * RANKK + (n1a ^ ((m & 7) << 3))] = f2bf(h0[r] * h0[r]);
            gb[m * RANKK + (n1b ^ ((m & 7) << 3))] = f2bf(h1[r] * h1[r]);
        }
        __syncthreads();   // gb ready; q0/q1 loads drained

        // ================= phase 2: Gamma = g @ W ===========================
        P2G(0, q0);  P2L(2, q0);
        P2G(1, q1);  P2L(3, q1);
        P2G(2, q0);  P2L(4, q0);
        P2G(3, q1);  P2L(5, q1);
        P2G(4, q0);  P2L(6, q0);
        P2G(5, q1);  P2L(7, q1);
        P2G(6, q0);  P2L(8, q0);
        P2G(7, q1);  P2L(9, q1);
        P2G(8, q0);  P2L(10, q0);
        P2G(9, q1);  P2L(11, q1);
        P2G(10, q0); P2L(12, q0);
        P2G(11, q1); P2L(13, q1);
        P2G(12, q0); P2L(14, q0);
        P2G(13, q1); P2L(15, q1);
        P2G(14, q0); P1L(0, pA);   // prefetch next accel's phase-1 groups 0,1
        P2G(15, q1); P1L(1, pB);

        // ================= epilogue: v,x update + vb refresh ================
        const int ph = j - (j / 3) * 3;
        const float ddt = ((ph == 1) ? D2F : D1F) * DTF;
        const float cdt = ((ph == 2) ? ((j == n_acc - 1) ? C1F : THETAF) : C2F) * DTF;
#pragma unroll
        for (int nt = 0; nt < 8; ++nt) {
#pragma unroll
            for (int r = 0; r < 4; ++r) {
                const int i = nt * 4 + r;
                const int m = g4 * 4 + r;
                const int n = wave * 128 + nt * 16 + m16;
                const float vn = vreg[i] + ddt * (freg[i] - acc[nt][r]);
                vreg[i] = vn;
                xreg[i] += cdt * vn;
                vb[m * DIMK + (n ^ ((m & 7) << 3))] = f2bf(vn);
            }
        }
        __syncthreads();   // vb ready; pA/pB loads drained
    }

    // ---- write out: x then v, f32
    float* xo = out;
    float* vo = out + (size_t)BROWS * DIMK;
#pragma unroll
    for (int nt = 0; nt < 8; ++nt) {
#pragma unroll
        for (int r = 0; r < 4; ++r) {
            const int i = nt * 4 + r;
            const int m = g4 * 4 + r;
            const int n = wave * 128 + nt * 16 + m16;
            const size_t gi = (size_t)(row0 + m) * DIMK + n;
            xo[gi] = xreg[i];
            vo[gi] = vreg[i];
        }
    }
}

extern "C" void kernel_launch(void* const* d_in, const int* in_sizes, int n_in,
                              void* d_out, int out_size, void* d_ws, size_t ws_size,
                              hipStream_t stream) {
    const float* x = (const float*)d_in[0];
    const float* v = (const float*)d_in[1];
    const float* f = (const float*)d_in[2];
    const float* U = (const float*)d_in[3];   // [1024][256]
    const float* W = (const float*)d_in[4];   // [256][1024]
    const int* steps = (const int*)d_in[5];

    ushort_t* Ut = (ushort_t*)d_ws;                    // [256][1024] bf16
    ushort_t* Wt = Ut + (size_t)RANKK * DIMK;          // [1024][256] bf16
    float* out = (float*)d_out;

    fr_transpose_cast<<<(DIMK / 32) * (RANKK / 32), 256, 0, stream>>>(U, Ut, DIMK, RANKK);
    fr_transpose_cast<<<(RANKK / 32) * (DIMK / 32), 256, 0, stream>>>(W, Wt, RANKK, DIMK);
    fr_kernel<<<BROWS / TROWS, 512, 0, stream>>>(x, v, f, Ut, Wt, steps, out);
}

// Round 4
// 772.711 us; speedup vs baseline: 1.0024x; 1.0024x over previous
//
#include <hip/hip_runtime.h>

typedef unsigned short ushort_t;
typedef unsigned int u32;
typedef float f32x4 __attribute__((ext_vector_type(4)));
typedef short s16x8 __attribute__((ext_vector_type(8)));

#define BROWS 4096
#define DIMK  1024
#define RANKK 256
#define TROWS 16
#define GPAD  264      // gb row pad: 264 us = 528 B (16B-aligned rows)
#define XPAD  1028     // xs row pad: 1028 f32 (breaks 32-bank aliasing)

#define DTF 0.01f
#define THETAF 1.35120719195965763f
#define C1F    0.675603595979828816f   // THETA/2
#define C2F   (-0.175603595979828816f) // (1-THETA)/2
#define D1F    1.35120719195965763f    // THETA
#define D2F   (-1.70241438391931526f)  // 1-2*THETA

__device__ __forceinline__ ushort_t f2bf(float f) {
    unsigned u = __builtin_bit_cast(unsigned, f);
    return (ushort_t)((u + 0x7FFFu + ((u >> 16) & 1u)) >> 16);
}
__device__ __forceinline__ u32 pack2bf(float lo, float hi) {
    return (u32)f2bf(lo) | ((u32)f2bf(hi) << 16);
}
__device__ __forceinline__ float unpk_lo(u32 u) {
    return __builtin_bit_cast(float, u << 16);
}
__device__ __forceinline__ float unpk_hi(u32 u) {
    return __builtin_bit_cast(float, u & 0xFFFF0000u);
}

// ---------------------------------------------------------------------------
// Transpose + cast f32 -> bf16:  out[c][r] = bf16(in[r][c]),  in is [R][C].
// ---------------------------------------------------------------------------
__global__ void fr_transpose_cast(const float* __restrict__ in,
                                  ushort_t* __restrict__ out, int R, int C) {
    __shared__ float tile[32][33];
    int tiles_c = C >> 5;
    int tr = blockIdx.x / tiles_c;
    int tc = blockIdx.x % tiles_c;
    int tx = threadIdx.x & 31;
    int ty = threadIdx.x >> 5;
#pragma unroll
    for (int i = 0; i < 32; i += 8)
        tile[ty + i][tx] = in[(size_t)(tr * 32 + ty + i) * C + tc * 32 + tx];
    __syncthreads();
#pragma unroll
    for (int i = 0; i < 32; i += 8)
        out[(size_t)(tc * 32 + ty + i) * R + tr * 32 + tx] = f2bf(tile[tx][ty + i]);
}

// ---------------------------------------------------------------------------
// Fused Forest-Ruth integrator. Block = 16 rows, 512 threads (8 waves).
// Per-lane 16B B-fragment loads (L2-resident) with a 4-buffer x 4-load
// rotating register prefetch (12-16 loads in flight). Register pressure
// kept under the 256-VGPR/2-waves-per-SIMD cap: x-accumulator in LDS,
// force packed as bf16 pairs.
// ---------------------------------------------------------------------------

// phase-1 group g (0..15) covers kk = 2g, 2g+1  (kel = kk*32 + g4*8)
#define P1L(g, BUF) do {                                                      \
    BUF[0] = b0p[(2 * (g)) * 4];                                              \
    BUF[1] = b1p[(2 * (g)) * 4];                                              \
    BUF[2] = b0p[(2 * (g) + 1) * 4];                                          \
    BUF[3] = b1p[(2 * (g) + 1) * 4];                                          \
} while (0)

#define P1G(g, BUF) do {                                                      \
    _Pragma("unroll")                                                         \
    for (int t = 0; t < 2; ++t) {                                             \
        const int kel_ = (2 * (g) + t) * 32 + g4 * 8;                         \
        const s16x8 a_ = *(const s16x8*)&vb[m16 * DIMK + (kel_ ^ swz)];       \
        h0 = __builtin_amdgcn_mfma_f32_16x16x32_bf16(a_, BUF[2 * t], h0, 0, 0, 0);     \
        h1 = __builtin_amdgcn_mfma_f32_16x16x32_bf16(a_, BUF[2 * t + 1], h1, 0, 0, 0); \
    }                                                                         \
} while (0)

// phase-2 slot s (0..15): kk = s>>1, half = s&1, nt = half*4 + q
#define P2L(s, BUF) do {                                                      \
    _Pragma("unroll")                                                         \
    for (int q = 0; q < 4; ++q)                                               \
        BUF[q] = bwp[((((s) & 1) * 4 + q)) * 512 + ((s) >> 1) * 4];           \
} while (0)

#define P2G(s, BUF) do {                                                      \
    const int kel_ = ((s) >> 1) * 32 + g4 * 8;                                \
    const s16x8 a_ = *(const s16x8*)&gb[m16 * GPAD + kel_];                   \
    _Pragma("unroll")                                                         \
    for (int q = 0; q < 4; ++q)                                               \
        acc[((s) & 1) * 4 + q] = __builtin_amdgcn_mfma_f32_16x16x32_bf16(     \
            a_, BUF[q], acc[((s) & 1) * 4 + q], 0, 0, 0);                     \
} while (0)

__global__ __launch_bounds__(512, 2) void fr_kernel(
    const float* __restrict__ x_in, const float* __restrict__ v_in,
    const float* __restrict__ f_in, const ushort_t* __restrict__ Ut,
    const ushort_t* __restrict__ Wt, const int* __restrict__ steps_p,
    float* __restrict__ out) {
    __shared__ ushort_t vb[TROWS * DIMK];    // 32 KB, XOR-swizzled rows
    __shared__ ushort_t gb[TROWS * GPAD];    // 8.25 KB, padded rows
    __shared__ float    xs[TROWS * XPAD];    // 64.25 KB, x accumulator

    const int tid  = threadIdx.x;
    const int lane = tid & 63;
    const int wave = tid >> 6;          // 0..7
    const int m16  = lane & 15;
    const int g4   = lane >> 4;         // 0..3
    const int swz  = (m16 & 7) << 3;
    const int row0 = blockIdx.x * TROWS;
    const int n_acc = 3 * steps_p[0];

    // fragment ownership: i = nt*4 + r;  m = g4*4 + r;  n = wave*128 + nt*16 + m16
    float vreg[32];
    u32 fpk[16];
#pragma unroll
    for (int nt = 0; nt < 8; ++nt) {
        float fv[4];
#pragma unroll
        for (int r = 0; r < 4; ++r) {
            const int m = g4 * 4 + r;
            const int n = wave * 128 + nt * 16 + m16;
            const size_t gi = (size_t)(row0 + m) * DIMK + n;
            const float v0 = v_in[gi];
            vreg[nt * 4 + r] = v0;
            xs[m * XPAD + n] = x_in[gi] + (C1F * DTF) * v0;  // first x-substep folded
            fv[r] = f_in[gi];
            vb[m * DIMK + (n ^ ((m & 7) << 3))] = f2bf(v0);
        }
        fpk[nt * 2]     = pack2bf(fv[0], fv[1]);
        fpk[nt * 2 + 1] = pack2bf(fv[2], fv[3]);
    }

    // B-fragment pointers (16-byte per-lane loads)
    const s16x8* b0p = (const s16x8*)(Ut + (size_t)(wave * 32 + m16) * DIMK + g4 * 8);
    const s16x8* b1p = b0p + (16 * DIMK) / 8;
    const s16x8* bwp = (const s16x8*)(Wt + (size_t)(wave * 128 + m16) * RANKK + g4 * 8);
    const int n1a = wave * 32 + m16, n1b = n1a + 16;

    s16x8 pA[4], pB[4], pC[4], pD[4];
    P1L(0, pA); P1L(1, pB); P1L(2, pC); P1L(3, pD);
    __syncthreads();   // vb/xs ready (prefetch drains too; one-time cost)

    for (int j = 0; j < n_acc; ++j) {
        // ================= phase 1: h = v @ U ===============================
        f32x4 h0 = {0.f, 0.f, 0.f, 0.f}, h1 = {0.f, 0.f, 0.f, 0.f};
        P1G(0, pA);  P1L(4, pA);
        P1G(1, pB);  P1L(5, pB);
        P1G(2, pC);  P1L(6, pC);
        P1G(3, pD);  P1L(7, pD);
        P1G(4, pA);  P1L(8, pA);
        P1G(5, pB);  P1L(9, pB);
        P1G(6, pC);  P1L(10, pC);
        P1G(7, pD);  P1L(11, pD);
        P1G(8, pA);  P1L(12, pA);
        P1G(9, pB);  P1L(13, pB);
        P1G(10, pC); P1L(14, pC);
        P1G(11, pD); P1L(15, pD);
        P1G(12, pA); P2L(0, pA);   // cross-phase prefetch
        P1G(13, pB); P2L(1, pB);
        P1G(14, pC); P2L(2, pC);
        P1G(15, pD); P2L(3, pD);

        // g = h*h -> gb (padded rows)
#pragma unroll
        for (int r = 0; r < 4; ++r) {
            const int m = g4 * 4 + r;
            gb[m * GPAD + n1a] = f2bf(h0[r] * h0[r]);
            gb[m * GPAD + n1b] = f2bf(h1[r] * h1[r]);
        }
        __syncthreads();   // gb ready (drains P2 slot-0..3 prefetches)

        // ================= phase 2: Gamma = g @ W ===========================
        f32x4 acc[8];
#pragma unroll
        for (int nt = 0; nt < 8; ++nt) acc[nt] = (f32x4){0.f, 0.f, 0.f, 0.f};
        P2G(0, pA);  P2L(4, pA);
        P2G(1, pB);  P2L(5, pB);
        P2G(2, pC);  P2L(6, pC);
        P2G(3, pD);  P2L(7, pD);
        P2G(4, pA);  P2L(8, pA);
        P2G(5, pB);  P2L(9, pB);
        P2G(6, pC);  P2L(10, pC);
        P2G(7, pD);  P2L(11, pD);
        P2G(8, pA);  P2L(12, pA);
        P2G(9, pB);  P2L(13, pB);
        P2G(10, pC); P2L(14, pC);
        P2G(11, pD); P2L(15, pD);
        P2G(12, pA); P1L(0, pA);   // prefetch next accel's phase-1
        P2G(13, pB); P1L(1, pB);
        P2G(14, pC); P1L(2, pC);
        P2G(15, pD); P1L(3, pD);

        // ================= epilogue: v,x update + vb refresh ================
        const int ph = j - (j / 3) * 3;
        const float ddt = ((ph == 1) ? D2F : D1F) * DTF;
        const float cdt = ((ph == 2) ? ((j == n_acc - 1) ? C1F : THETAF) : C2F) * DTF;
#pragma unroll
        for (int nt = 0; nt < 8; ++nt) {
#pragma unroll
            for (int r = 0; r < 4; ++r) {
                const int i = nt * 4 + r;
                const int m = g4 * 4 + r;
                const int n = wave * 128 + nt * 16 + m16;
                const float fi = (r & 1) ? unpk_hi(fpk[nt * 2 + (r >> 1)])
                                         : unpk_lo(fpk[nt * 2 + (r >> 1)]);
                const float vn = vreg[i] + ddt * (fi - acc[nt][r]);
                vreg[i] = vn;
                xs[m * XPAD + n] += cdt * vn;   // thread-exclusive element
                vb[m * DIMK + (n ^ ((m & 7) << 3))] = f2bf(vn);
            }
        }
        __syncthreads();   // vb ready for next phase-1
    }

    // ---- write out: x then v, f32
    float* xo = out;
    float* vo = out + (size_t)BROWS * DIMK;
#pragma unroll
    for (int nt = 0; nt < 8; ++nt) {
#pragma unroll
        for (int r = 0; r < 4; ++r) {
            const int i = nt * 4 + r;
            const int m = g4 * 4 + r;
            const int n = wave * 128 + nt * 16 + m16;
            const size_t gi = (size_t)(row0 + m) * DIMK + n;
            xo[gi] = xs[m * XPAD + n];
            vo[gi] = vreg[i];
        }
    }
}

extern "C" void kernel_launch(void* const* d_in, const int* in_sizes, int n_in,
                              void* d_out, int out_size, void* d_ws, size_t ws_size,
                              hipStream_t stream) {
    const float* x = (const float*)d_in[0];
    const float* v = (const float*)d_in[1];
    const float* f = (const float*)d_in[2];
    const float* U = (const float*)d_in[3];   // [1024][256]
    const float* W = (const float*)d_in[4];   // [256][1024]
    const int* steps = (const int*)d_in[5];

    ushort_t* Ut = (ushort_t*)d_ws;                    // [256][1024] bf16
    ushort_t* Wt = Ut + (size_t)RANKK * DIMK;          // [1024][256] bf16
    float* out = (float*)d_out;

    fr_transpose_cast<<<(DIMK / 32) * (RANKK / 32), 256, 0, stream>>>(U, Ut, DIMK, RANKK);
    fr_transpose_cast<<<(RANKK / 32) * (DIMK / 32), 256, 0, stream>>>(W, Wt, RANKK, DIMK);
    fr_kernel<<<BROWS / TROWS, 512, 0, stream>>>(x, v, f, Ut, Wt, steps, out);
}

// Round 5
// 725.829 us; speedup vs baseline: 1.0672x; 1.0646x over previous
//
#include <hip/hip_runtime.h>

typedef unsigned short ushort_t;
typedef unsigned int u32;
typedef float f32x4 __attribute__((ext_vector_type(4)));
typedef short s16x8 __attribute__((ext_vector_type(8)));

#define BROWS 4096
#define DIMK  1024
#define RANKK 256
#define TROWS 16
#define GPAD  264      // gb row pad: 264 us = 528 B (16B-aligned rows)
#define XPAD  1028     // xs row pad: 1028 f32 (breaks 32-bank aliasing)

#define DTF 0.01f
#define THETAF 1.35120719195965763f
#define C1F    0.675603595979828816f   // THETA/2
#define C2F   (-0.175603595979828816f) // (1-THETA)/2
#define D1F    1.35120719195965763f    // THETA
#define D2F   (-1.70241438391931526f)  // 1-2*THETA

__device__ __forceinline__ ushort_t f2bf(float f) {
    unsigned u = __builtin_bit_cast(unsigned, f);
    return (ushort_t)((u + 0x7FFFu + ((u >> 16) & 1u)) >> 16);
}
__device__ __forceinline__ u32 pack2bf(float lo, float hi) {
    return (u32)f2bf(lo) | ((u32)f2bf(hi) << 16);
}
__device__ __forceinline__ float unpk_lo(u32 u) {
    return __builtin_bit_cast(float, u << 16);
}
__device__ __forceinline__ float unpk_hi(u32 u) {
    return __builtin_bit_cast(float, u & 0xFFFF0000u);
}

// ---------------------------------------------------------------------------
// Transpose + cast f32 -> bf16:  out[c][r] = bf16(in[r][c]),  in is [R][C].
// ---------------------------------------------------------------------------
__global__ void fr_transpose_cast(const float* __restrict__ in,
                                  ushort_t* __restrict__ out, int R, int C) {
    __shared__ float tile[32][33];
    int tiles_c = C >> 5;
    int tr = blockIdx.x / tiles_c;
    int tc = blockIdx.x % tiles_c;
    int tx = threadIdx.x & 31;
    int ty = threadIdx.x >> 5;
#pragma unroll
    for (int i = 0; i < 32; i += 8)
        tile[ty + i][tx] = in[(size_t)(tr * 32 + ty + i) * C + tc * 32 + tx];
    __syncthreads();
#pragma unroll
    for (int i = 0; i < 32; i += 8)
        out[(size_t)(tc * 32 + ty + i) * R + tr * 32 + tx] = f2bf(tile[tx][ty + i]);
}

// ---------------------------------------------------------------------------
// Fused Forest-Ruth integrator. Block = 16 rows, 512 threads (8 waves).
// Per-lane 16B B-fragment loads (L2-resident) with a TWO-buffer rotating
// register prefetch (4-8 loads in flight; compiler emits counted vmcnt(4)).
// Register budget: ~105 arch VGPRs + AGPR accumulators -> no spill at 128.
// x-accumulator lives in LDS; force packed as bf16 pairs.
// ---------------------------------------------------------------------------

// phase-1 group g (0..15) covers kk = 2g, 2g+1  (kel = kk*32 + g4*8)
#define P1L(g, BUF) do {                                                      \
    BUF[0] = b0p[(2 * (g)) * 4];                                              \
    BUF[1] = b1p[(2 * (g)) * 4];                                              \
    BUF[2] = b0p[(2 * (g) + 1) * 4];                                          \
    BUF[3] = b1p[(2 * (g) + 1) * 4];                                          \
} while (0)

#define P1G(g, BUF) do {                                                      \
    _Pragma("unroll")                                                         \
    for (int t = 0; t < 2; ++t) {                                             \
        const int kel_ = (2 * (g) + t) * 32 + g4 * 8;                         \
        const s16x8 a_ = *(const s16x8*)&vb[m16 * DIMK + (kel_ ^ swz)];       \
        h0 = __builtin_amdgcn_mfma_f32_16x16x32_bf16(a_, BUF[2 * t], h0, 0, 0, 0);     \
        h1 = __builtin_amdgcn_mfma_f32_16x16x32_bf16(a_, BUF[2 * t + 1], h1, 0, 0, 0); \
    }                                                                         \
} while (0)

// phase-2 slot s (0..15): kk = s>>1, half = s&1, nt = half*4 + q
#define P2L(s, BUF) do {                                                      \
    _Pragma("unroll")                                                         \
    for (int q = 0; q < 4; ++q)                                               \
        BUF[q] = bwp[((((s) & 1) * 4 + q)) * 512 + ((s) >> 1) * 4];           \
} while (0)

#define P2G(s, BUF) do {                                                      \
    const int kel_ = ((s) >> 1) * 32 + g4 * 8;                                \
    const s16x8 a_ = *(const s16x8*)&gb[m16 * GPAD + kel_];                   \
    _Pragma("unroll")                                                         \
    for (int q = 0; q < 4; ++q)                                               \
        acc[((s) & 1) * 4 + q] = __builtin_amdgcn_mfma_f32_16x16x32_bf16(     \
            a_, BUF[q], acc[((s) & 1) * 4 + q], 0, 0, 0);                     \
} while (0)

__global__ __launch_bounds__(512, 2) void fr_kernel(
    const float* __restrict__ x_in, const float* __restrict__ v_in,
    const float* __restrict__ f_in, const ushort_t* __restrict__ Ut,
    const ushort_t* __restrict__ Wt, const int* __restrict__ steps_p,
    float* __restrict__ out) {
    __shared__ ushort_t vb[TROWS * DIMK];    // 32 KB, XOR-swizzled rows
    __shared__ ushort_t gb[TROWS * GPAD];    // 8.25 KB, padded rows
    __shared__ float    xs[TROWS * XPAD];    // 64.25 KB, x accumulator

    const int tid  = threadIdx.x;
    const int lane = tid & 63;
    const int wave = tid >> 6;          // 0..7
    const int m16  = lane & 15;
    const int g4   = lane >> 4;         // 0..3
    const int swz  = (m16 & 7) << 3;
    const int row0 = blockIdx.x * TROWS;
    const int n_acc = 3 * steps_p[0];

    // fragment ownership: i = nt*4 + r;  m = g4*4 + r;  n = wave*128 + nt*16 + m16
    float vreg[32];
    u32 fpk[16];
#pragma unroll
    for (int nt = 0; nt < 8; ++nt) {
        float fv[4];
#pragma unroll
        for (int r = 0; r < 4; ++r) {
            const int m = g4 * 4 + r;
            const int n = wave * 128 + nt * 16 + m16;
            const size_t gi = (size_t)(row0 + m) * DIMK + n;
            const float v0 = v_in[gi];
            vreg[nt * 4 + r] = v0;
            xs[m * XPAD + n] = x_in[gi] + (C1F * DTF) * v0;  // first x-substep folded
            fv[r] = f_in[gi];
            vb[m * DIMK + (n ^ ((m & 7) << 3))] = f2bf(v0);
        }
        fpk[nt * 2]     = pack2bf(fv[0], fv[1]);
        fpk[nt * 2 + 1] = pack2bf(fv[2], fv[3]);
    }

    // B-fragment pointers (16-byte per-lane loads)
    const s16x8* b0p = (const s16x8*)(Ut + (size_t)(wave * 32 + m16) * DIMK + g4 * 8);
    const s16x8* b1p = b0p + (16 * DIMK) / 8;
    const s16x8* bwp = (const s16x8*)(Wt + (size_t)(wave * 128 + m16) * RANKK + g4 * 8);
    const int n1a = wave * 32 + m16, n1b = n1a + 16;

    s16x8 pA[4], pB[4];
    P1L(0, pA); P1L(1, pB);
    __syncthreads();   // vb/xs ready (drains prologue prefetch; one-time cost)

    for (int j = 0; j < n_acc; ++j) {
        // ================= phase 1: h = v @ U ===============================
        f32x4 h0 = {0.f, 0.f, 0.f, 0.f}, h1 = {0.f, 0.f, 0.f, 0.f};
        P1G(0, pA);  P1L(2, pA);
        P1G(1, pB);  P1L(3, pB);
        P1G(2, pA);  P1L(4, pA);
        P1G(3, pB);  P1L(5, pB);
        P1G(4, pA);  P1L(6, pA);
        P1G(5, pB);  P1L(7, pB);
        P1G(6, pA);  P1L(8, pA);
        P1G(7, pB);  P1L(9, pB);
        P1G(8, pA);  P1L(10, pA);
        P1G(9, pB);  P1L(11, pB);
        P1G(10, pA); P1L(12, pA);
        P1G(11, pB); P1L(13, pB);
        P1G(12, pA); P1L(14, pA);
        P1G(13, pB); P1L(15, pB);
        P1G(14, pA); P2L(0, pA);   // cross-phase prefetch
        P1G(15, pB); P2L(1, pB);

        // g = h*h -> gb (padded rows)
#pragma unroll
        for (int r = 0; r < 4; ++r) {
            const int m = g4 * 4 + r;
            gb[m * GPAD + n1a] = f2bf(h0[r] * h0[r]);
            gb[m * GPAD + n1b] = f2bf(h1[r] * h1[r]);
        }
        __syncthreads();   // gb ready (drains P2 slot-0/1 prefetch)

        // ================= phase 2: Gamma = g @ W ===========================
        f32x4 acc[8];
#pragma unroll
        for (int nt = 0; nt < 8; ++nt) acc[nt] = (f32x4){0.f, 0.f, 0.f, 0.f};
        P2G(0, pA);  P2L(2, pA);
        P2G(1, pB);  P2L(3, pB);
        P2G(2, pA);  P2L(4, pA);
        P2G(3, pB);  P2L(5, pB);
        P2G(4, pA);  P2L(6, pA);
        P2G(5, pB);  P2L(7, pB);
        P2G(6, pA);  P2L(8, pA);
        P2G(7, pB);  P2L(9, pB);
        P2G(8, pA);  P2L(10, pA);
        P2G(9, pB);  P2L(11, pB);
        P2G(10, pA); P2L(12, pA);
        P2G(11, pB); P2L(13, pB);
        P2G(12, pA); P2L(14, pA);
        P2G(13, pB); P2L(15, pB);
        P2G(14, pA); P1L(0, pA);   // prefetch next accel's phase-1
        P2G(15, pB); P1L(1, pB);

        // ================= epilogue: v,x update + vb refresh ================
        const int ph = j - (j / 3) * 3;
        const float ddt = ((ph == 1) ? D2F : D1F) * DTF;
        const float cdt = ((ph == 2) ? ((j == n_acc - 1) ? C1F : THETAF) : C2F) * DTF;
#pragma unroll
        for (int nt = 0; nt < 8; ++nt) {
#pragma unroll
            for (int r = 0; r < 4; ++r) {
                const int i = nt * 4 + r;
                const int m = g4 * 4 + r;
                const int n = wave * 128 + nt * 16 + m16;
                const float fi = (r & 1) ? unpk_hi(fpk[nt * 2 + (r >> 1)])
                                         : unpk_lo(fpk[nt * 2 + (r >> 1)]);
                const float vn = vreg[i] + ddt * (fi - acc[nt][r]);
                vreg[i] = vn;
                xs[m * XPAD + n] += cdt * vn;   // thread-exclusive element
                vb[m * DIMK + (n ^ ((m & 7) << 3))] = f2bf(vn);
            }
        }
        __syncthreads();   // vb ready for next phase-1
    }

    // ---- write out: x then v, f32
    float* xo = out;
    float* vo = out + (size_t)BROWS * DIMK;
#pragma unroll
    for (int nt = 0; nt < 8; ++nt) {
#pragma unroll
        for (int r = 0; r < 4; ++r) {
            const int i = nt * 4 + r;
            const int m = g4 * 4 + r;
            const int n = wave * 128 + nt * 16 + m16;
            const size_t gi = (size_t)(row0 + m) * DIMK + n;
            xo[gi] = xs[m * XPAD + n];
            vo[gi] = vreg[i];
        }
    }
}

extern "C" void kernel_launch(void* const* d_in, const int* in_sizes, int n_in,
                              void* d_out, int out_size, void* d_ws, size_t ws_size,
                              hipStream_t stream) {
    const float* x = (const float*)d_in[0];
    const float* v = (const float*)d_in[1];
    const float* f = (const float*)d_in[2];
    const float* U = (const float*)d_in[3];   // [1024][256]
    const float* W = (const float*)d_in[4];   // [256][1024]
    const int* steps = (const int*)d_in[5];

    ushort_t* Ut = (ushort_t*)d_ws;                    // [256][1024] bf16
    ushort_t* Wt = Ut + (size_t)RANKK * DIMK;          // [1024][256] bf16
    float* out = (float*)d_out;

    fr_transpose_cast<<<(DIMK / 32) * (RANKK / 32), 256, 0, stream>>>(U, Ut, DIMK, RANKK);
    fr_transpose_cast<<<(RANKK / 32) * (DIMK / 32), 256, 0, stream>>>(W, Wt, RANKK, DIMK);
    fr_kernel<<<BROWS / TROWS, 512, 0, stream>>>(x, v, f, Ut, Wt, steps, out);
}